// Round 4
// baseline (144.551 us; speedup 1.0000x reference)
//
#include <hip/hip_runtime.h>
#include <math.h>

#define LRELU(v) ((v) > 0.f ? (v) : 0.2f * (v))
#define LOG2E 1.44269504088896340736f

// ---------------------------------------------------------------------------
// K1: h1 = lrelu(x@W1+b1) [1024,256]; h2 = h1@W2+b2 [1024,128]; BN stats.
// 512 blocks x 256 threads, 2 rows/block. (unchanged, verified)
// ---------------------------------------------------------------------------
__global__ __launch_bounds__(256) void k1_mlp12(
    const float* __restrict__ x,
    const float* __restrict__ W1, const float* __restrict__ b1,
    const float* __restrict__ W2, const float* __restrict__ b2,
    float* __restrict__ h2g, float* __restrict__ stats)
{
    __shared__ float xs[256];
    __shared__ float h1s[512];
    __shared__ float ssum[256];
    __shared__ float ssq[256];
    const int t = threadIdx.x;
    const int r0 = blockIdx.x * 2;

    xs[t] = x[r0 * 128 + t];                    // 2 rows of x, coalesced
    __syncthreads();

    // h1: thread t = column, both rows share the W1 load
    {
        float a0 = b1[t], a1 = a0;
        for (int k = 0; k < 128; ++k) {
            float w = W1[k * 256 + t];          // coalesced
            a0 += xs[k] * w;
            a1 += xs[128 + k] * w;
        }
        h1s[t] = LRELU(a0);
        h1s[256 + t] = LRELU(a1);
    }
    __syncthreads();

    // h2: thread (c = t&127, rr = t>>7) -> one output
    {
        const int c = t & 127;
        const int rr = t >> 7;
        float a = b2[c];
        for (int k = 0; k < 256; ++k)
            a += h1s[rr * 256 + k] * W2[k * 128 + c];
        h2g[(r0 + rr) * 128 + c] = a;
        ssum[t] = a;                            // t == rr*128 + c
        ssq[t] = a * a;
    }
    __syncthreads();
    if (t < 128)      atomicAdd(stats + t, ssum[t] + ssum[128 + t]);
    else { int c = t - 128; atomicAdd(stats + 128 + c, ssq[c] + ssq[128 + c]); }
}

// ---------------------------------------------------------------------------
// K2: BN+lrelu -> h3 -> attn(seq=1) -> h4 -> Mt = (h4@T2)^T * log2(e),
// PLUS score base = h4.Ws[0:64] + bs - sum_c Ws[64+c]  (K4's h-part folded).
// Mt pre-scaled by log2(e) so K3 uses a bare v_exp_f32 (2^x) per term.
// Mt[260][1024] col-major, rows 250..259 zeroed (K3 ct=12 pad).
// ---------------------------------------------------------------------------
__global__ __launch_bounds__(256) void k2_bn_attn_m(
    const float* __restrict__ h2g, const float* __restrict__ stats,
    const float* __restrict__ gamma, const float* __restrict__ beta,
    const float* __restrict__ W3, const float* __restrict__ b3,
    const float* __restrict__ Wv, const float* __restrict__ bv,
    const float* __restrict__ Wo, const float* __restrict__ bo,
    const float* __restrict__ T2,
    const float* __restrict__ Wsc, const float* __restrict__ bs,
    float* __restrict__ Mt, float* __restrict__ score)
{
    __shared__ float a[256];                    // [2 rows][128]
    __shared__ float h3s[128];                  // [2][64]
    __shared__ float vss[128];
    __shared__ float h4s[128];
    __shared__ float red[4];
    const int t = threadIdx.x;
    const int r0 = blockIdx.x * 2;

    // BN (batch stats) + lrelu: t = rr*128 + c
    {
        const int c = t & 127;
        float s = stats[c], ss = stats[128 + c];
        float mean = s * (1.f / 1024.f);
        float var = ss * (1.f / 1024.f) - mean * mean;
        float rstd = rsqrtf(var + 1e-5f);
        float v = (h2g[r0 * 128 + t] - mean) * rstd * gamma[c] + beta[c];
        a[t] = LRELU(v);
    }
    __syncthreads();

    const int row = t >> 6, col = t & 63;       // valid for t < 128
    // h3 = lrelu(a@W3+b3)
    if (t < 128) {
        float acc = b3[col];
        for (int k = 0; k < 128; ++k) acc += a[row * 128 + k] * W3[k * 64 + col];
        h3s[row * 64 + col] = LRELU(acc);
    }
    __syncthreads();
    // v = h3@Wv+bv ; then h4 = h3 + v@Wo + bo
    if (t < 128) {
        float acc = bv[col];
        for (int k = 0; k < 64; ++k) acc += h3s[row * 64 + k] * Wv[k * 64 + col];
        vss[row * 64 + col] = acc;
    }
    __syncthreads();
    if (t < 128) {
        float acc = bo[col];
        for (int k = 0; k < 64; ++k) acc += vss[row * 64 + k] * Wo[k * 64 + col];
        h4s[row * 64 + col] = h3s[row * 64 + col] + acc;
    }
    __syncthreads();

    // Mt[col][r0 / r0+1], pre-scaled by log2(e); rows 250..259 zero pad.
    if (t < 250) {
        float m0 = 0.f, m1 = 0.f;
        for (int k = 0; k < 64; ++k) {
            float w = T2[k * 250 + t];          // coalesced across t
            m0 += h4s[k] * w;
            m1 += h4s[64 + k] * w;
        }
        Mt[(size_t)t * 1024 + r0]     = m0 * LOG2E;
        Mt[(size_t)t * 1024 + r0 + 1] = m1 * LOG2E;
    } else {
        Mt[(size_t)t * 1024 + r0]     = 0.f;
        Mt[(size_t)t * 1024 + r0 + 1] = 0.f;
    }
    if (t < 4) {
        Mt[(size_t)(256 + t) * 1024 + r0]     = 0.f;
        Mt[(size_t)(256 + t) * 1024 + r0 + 1] = 0.f;
    }

    // score base: wave0 -> row0 dot, wave1 -> row1 dot, wave2 -> sum Ws[64:114]
    float contrib = 0.f;
    if (t < 128)            contrib = h4s[t] * Wsc[col];
    else if (t < 192) { int c2 = t & 63; contrib = (c2 < 50) ? Wsc[64 + c2] : 0.f; }
    for (int off = 32; off > 0; off >>= 1)
        contrib += __shfl_down(contrib, off, 64);
    if ((t & 63) == 0) red[t >> 6] = contrib;
    __syncthreads();
    // self-term exp(0)=1 per channel is included in K3's sums; subtract
    // sum_c Ws[64+c] (red[2]) here once.
    if (t < 2) score[r0 + t] = red[t] + bs[0] - red[2];
}

// ---------------------------------------------------------------------------
// K3: all-pairs L1 + exp2 (Mt pre-scaled by log2 e). One (j,c) per thread.
// Grid = 16 jt x 13 ct x 8 ic = 1664 blocks (~26 waves/CU).
// float4 LDS broadcast reads (verified round 3). Per-block LDS reduction
// over the 4 channel-lanes -> ONE atomicAdd per (block, j): 106K atomics,
// ~104/address, hidden under compute. K4 eliminated.
// ---------------------------------------------------------------------------
__global__ __launch_bounds__(256) void k3_pairs(
    const float* __restrict__ Mt, const float* __restrict__ Wsc,
    float* __restrict__ score)
{
    __shared__ float mi[2560];                  // [20 cols][128 i]
    __shared__ float sred[256];
    const int t = threadIdx.x;
    const int b = blockIdx.x;
    const int jt = b / 104;
    const int rem = b - jt * 104;
    const int ct = rem >> 3;
    const int ic = rem & 7;
    const int jl = t & 63, cl = t >> 6;
    const int j = jt * 64 + jl;
    const int c = ct * 4 + cl;                  // 0..51 (50,51 are zero pad)
    const int i0 = ic * 128;

    // stage 20 rows x 128 i as float2 (coalesced, 5 iters)
    for (int qq = 0; qq < 5; ++qq) {
        int idx = qq * 256 + t;                 // 0..1279 float2 slots
        int cc = idx >> 6, il = idx & 63;
        *(float2*)(mi + cc * 128 + il * 2) =
            *(const float2*)(Mt + (size_t)(ct * 20 + cc) * 1024 + i0 + il * 2);
    }

    float mj0 = Mt[(size_t)(c * 5 + 0) * 1024 + j];
    float mj1 = Mt[(size_t)(c * 5 + 1) * 1024 + j];
    float mj2 = Mt[(size_t)(c * 5 + 2) * 1024 + j];
    float mj3 = Mt[(size_t)(c * 5 + 3) * 1024 + j];
    float mj4 = Mt[(size_t)(c * 5 + 4) * 1024 + j];
    __syncthreads();

    const float4* m0 = (const float4*)(mi + (cl * 5 + 0) * 128);
    const float4* m1 = (const float4*)(mi + (cl * 5 + 1) * 128);
    const float4* m2 = (const float4*)(mi + (cl * 5 + 2) * 128);
    const float4* m3 = (const float4*)(mi + (cl * 5 + 3) * 128);
    const float4* m4 = (const float4*)(mi + (cl * 5 + 4) * 128);

    float acc0 = 0.f, acc1 = 0.f, acc2 = 0.f, acc3 = 0.f;
    for (int p = 0; p < 32; ++p) {
        float4 v0 = m0[p], v1 = m1[p], v2 = m2[p], v3 = m3[p], v4 = m4[p];
        float d0 = fabsf(v0.x - mj0) + fabsf(v1.x - mj1) + fabsf(v2.x - mj2)
                 + fabsf(v3.x - mj3) + fabsf(v4.x - mj4);
        float d1 = fabsf(v0.y - mj0) + fabsf(v1.y - mj1) + fabsf(v2.y - mj2)
                 + fabsf(v3.y - mj3) + fabsf(v4.y - mj4);
        float d2 = fabsf(v0.z - mj0) + fabsf(v1.z - mj1) + fabsf(v2.z - mj2)
                 + fabsf(v3.z - mj3) + fabsf(v4.z - mj4);
        float d3 = fabsf(v0.w - mj0) + fabsf(v1.w - mj1) + fabsf(v2.w - mj2)
                 + fabsf(v3.w - mj3) + fabsf(v4.w - mj4);
        acc0 += exp2f(-d0);
        acc1 += exp2f(-d1);
        acc2 += exp2f(-d2);
        acc3 += exp2f(-d3);
    }
    // weight by Ws[64+c] (pad channels c>=50 get weight 0), reduce the 4
    // channel-lanes per j through LDS, single atomic per (block, j).
    float w = (c < 50) ? Wsc[64 + c] : 0.f;
    sred[t] = ((acc0 + acc1) + (acc2 + acc3)) * w;
    __syncthreads();
    if (t < 64) {
        float s = (sred[t] + sred[64 + t]) + (sred[128 + t] + sred[192 + t]);
        atomicAdd(score + jt * 64 + t, s);
    }
}

// ---------------------------------------------------------------------------
// ws layout (float offsets):
//   h2    @ 0       (131072)
//   stats @ 131072  (256)
//   Mt    @ 131328  (260*1024 = 266240, col-major transpose of M, *log2e)
// K4 / opart / h4 eliminated: K2 writes the score base to d_out, K3
// accumulates the minibatch-discrimination part with device atomics.
// ---------------------------------------------------------------------------
extern "C" void kernel_launch(void* const* d_in, const int* in_sizes, int n_in,
                              void* d_out, int out_size, void* d_ws, size_t ws_size,
                              hipStream_t stream)
{
    const float* x     = (const float*)d_in[0];
    const float* W1    = (const float*)d_in[1];
    const float* b1    = (const float*)d_in[2];
    const float* W2    = (const float*)d_in[3];
    const float* b2    = (const float*)d_in[4];
    const float* gamma = (const float*)d_in[5];
    const float* beta  = (const float*)d_in[6];
    const float* W3    = (const float*)d_in[7];
    const float* b3    = (const float*)d_in[8];
    const float* Wv    = (const float*)d_in[9];
    const float* bv    = (const float*)d_in[10];
    const float* Wo    = (const float*)d_in[11];
    const float* bo    = (const float*)d_in[12];
    const float* T2    = (const float*)d_in[13];
    const float* Ws    = (const float*)d_in[14];
    const float* bs    = (const float*)d_in[15];

    float* ws    = (float*)d_ws;
    float* h2    = ws + 0;
    float* stats = ws + 131072;
    float* Mt    = ws + 131328;
    float* out   = (float*)d_out;

    hipMemsetAsync(stats, 0, 256 * sizeof(float), stream);
    hipLaunchKernelGGL(k1_mlp12, dim3(512), dim3(256), 0, stream,
                       x, W1, b1, W2, b2, h2, stats);
    hipLaunchKernelGGL(k2_bn_attn_m, dim3(512), dim3(256), 0, stream,
                       h2, stats, gamma, beta, W3, b3, Wv, bv, Wo, bo, T2,
                       Ws, bs, Mt, out);
    hipLaunchKernelGGL(k3_pairs, dim3(1664), dim3(256), 0, stream, Mt, Ws, out);
}

// Round 5
// 140.878 us; speedup vs baseline: 1.0261x; 1.0261x over previous
//
#include <hip/hip_runtime.h>
#include <math.h>

#define LRELU(v) ((v) > 0.f ? (v) : 0.2f * (v))

// ---------------------------------------------------------------------------
// K1: h1 = lrelu(x@W1+b1) [1024,256]; h2 = h1@W2+b2 [1024,128]; BN stats.
// 512 blocks x 256 threads, 2 rows/block. (unchanged, verified)
// ---------------------------------------------------------------------------
__global__ __launch_bounds__(256) void k1_mlp12(
    const float* __restrict__ x,
    const float* __restrict__ W1, const float* __restrict__ b1,
    const float* __restrict__ W2, const float* __restrict__ b2,
    float* __restrict__ h2g, float* __restrict__ stats)
{
    __shared__ float xs[256];
    __shared__ float h1s[512];
    __shared__ float ssum[256];
    __shared__ float ssq[256];
    const int t = threadIdx.x;
    const int r0 = blockIdx.x * 2;

    xs[t] = x[r0 * 128 + t];                    // 2 rows of x, coalesced
    __syncthreads();

    // h1: thread t = column, both rows share the W1 load
    {
        float a0 = b1[t], a1 = a0;
        for (int k = 0; k < 128; ++k) {
            float w = W1[k * 256 + t];          // coalesced
            a0 += xs[k] * w;
            a1 += xs[128 + k] * w;
        }
        h1s[t] = LRELU(a0);
        h1s[256 + t] = LRELU(a1);
    }
    __syncthreads();

    // h2: thread (c = t&127, rr = t>>7) -> one output
    {
        const int c = t & 127;
        const int rr = t >> 7;
        float a = b2[c];
        for (int k = 0; k < 256; ++k)
            a += h1s[rr * 256 + k] * W2[k * 128 + c];
        h2g[(r0 + rr) * 128 + c] = a;
        ssum[t] = a;                            // t == rr*128 + c
        ssq[t] = a * a;
    }
    __syncthreads();
    if (t < 128)      atomicAdd(stats + t, ssum[t] + ssum[128 + t]);
    else { int c = t - 128; atomicAdd(stats + 128 + c, ssq[c] + ssq[128 + c]); }
}

// ---------------------------------------------------------------------------
// K2: BN+lrelu -> h3 -> attn(seq=1) -> h4 -> Mt = (h4@T2)^T (UNscaled),
// PLUS score base = h4.Ws[0:64] + bs - sum_c Ws[64+c]  (K4's h-part folded).
// Mt[260][1024] col-major, rows 250..259 zeroed (K3 ct=12 pad).
// ---------------------------------------------------------------------------
__global__ __launch_bounds__(256) void k2_bn_attn_m(
    const float* __restrict__ h2g, const float* __restrict__ stats,
    const float* __restrict__ gamma, const float* __restrict__ beta,
    const float* __restrict__ W3, const float* __restrict__ b3,
    const float* __restrict__ Wv, const float* __restrict__ bv,
    const float* __restrict__ Wo, const float* __restrict__ bo,
    const float* __restrict__ T2,
    const float* __restrict__ Wsc, const float* __restrict__ bs,
    float* __restrict__ Mt, float* __restrict__ score)
{
    __shared__ float a[256];                    // [2 rows][128]
    __shared__ float h3s[128];                  // [2][64]
    __shared__ float vss[128];
    __shared__ float h4s[128];
    __shared__ float red[4];
    const int t = threadIdx.x;
    const int r0 = blockIdx.x * 2;

    // BN (batch stats) + lrelu: t = rr*128 + c
    {
        const int c = t & 127;
        float s = stats[c], ss = stats[128 + c];
        float mean = s * (1.f / 1024.f);
        float var = ss * (1.f / 1024.f) - mean * mean;
        float rstd = rsqrtf(var + 1e-5f);
        float v = (h2g[r0 * 128 + t] - mean) * rstd * gamma[c] + beta[c];
        a[t] = LRELU(v);
    }
    __syncthreads();

    const int row = t >> 6, col = t & 63;       // valid for t < 128
    // h3 = lrelu(a@W3+b3)
    if (t < 128) {
        float acc = b3[col];
        for (int k = 0; k < 128; ++k) acc += a[row * 128 + k] * W3[k * 64 + col];
        h3s[row * 64 + col] = LRELU(acc);
    }
    __syncthreads();
    // v = h3@Wv+bv ; then h4 = h3 + v@Wo + bo
    if (t < 128) {
        float acc = bv[col];
        for (int k = 0; k < 64; ++k) acc += h3s[row * 64 + k] * Wv[k * 64 + col];
        vss[row * 64 + col] = acc;
    }
    __syncthreads();
    if (t < 128) {
        float acc = bo[col];
        for (int k = 0; k < 64; ++k) acc += vss[row * 64 + k] * Wo[k * 64 + col];
        h4s[row * 64 + col] = h3s[row * 64 + col] + acc;
    }
    __syncthreads();

    // Mt[col][r0 / r0+1]; rows 250..259 zero pad. Each T2 load feeds both rows.
    if (t < 250) {
        float m0 = 0.f, m1 = 0.f;
        for (int k = 0; k < 64; ++k) {
            float w = T2[k * 250 + t];          // coalesced across t
            m0 += h4s[k] * w;
            m1 += h4s[64 + k] * w;
        }
        Mt[(size_t)t * 1024 + r0]     = m0;
        Mt[(size_t)t * 1024 + r0 + 1] = m1;
    } else {
        Mt[(size_t)t * 1024 + r0]     = 0.f;
        Mt[(size_t)t * 1024 + r0 + 1] = 0.f;
    }
    if (t < 4) {
        Mt[(size_t)(256 + t) * 1024 + r0]     = 0.f;
        Mt[(size_t)(256 + t) * 1024 + r0 + 1] = 0.f;
    }

    // score base: wave0 -> row0 dot, wave1 -> row1 dot, wave2 -> sum Ws[64:114]
    float contrib = 0.f;
    if (t < 128)            contrib = h4s[t] * Wsc[col];
    else if (t < 192) { int c2 = t & 63; contrib = (c2 < 50) ? Wsc[64 + c2] : 0.f; }
    for (int off = 32; off > 0; off >>= 1)
        contrib += __shfl_down(contrib, off, 64);
    if ((t & 63) == 0) red[t >> 6] = contrib;
    __syncthreads();
    // self-term exp(0)=1 per channel is included in K3's sums; subtract
    // sum_c Ws[64+c] (red[2]) here once.
    if (t < 2) score[r0 + t] = red[t] + bs[0] - red[2];
}

// ---------------------------------------------------------------------------
// K3: all-pairs L1 + __expf (fast v_exp path, verified round 3).
// Grid = 16 jt x 13 ct x 8 ic = 1664 blocks (~26 waves/CU).
// float4 LDS broadcast reads. Per-block LDS reduction over the 4
// channel-lanes -> ONE atomicAdd per (block, j): 106K atomics total,
// ~104/address, hidden under compute. K4 eliminated.
// ---------------------------------------------------------------------------
__global__ __launch_bounds__(256) void k3_pairs(
    const float* __restrict__ Mt, const float* __restrict__ Wsc,
    float* __restrict__ score)
{
    __shared__ float mi[2560];                  // [20 cols][128 i]
    __shared__ float sred[256];
    const int t = threadIdx.x;
    const int b = blockIdx.x;
    const int jt = b / 104;
    const int rem = b - jt * 104;
    const int ct = rem >> 3;
    const int ic = rem & 7;
    const int jl = t & 63, cl = t >> 6;
    const int j = jt * 64 + jl;
    const int c = ct * 4 + cl;                  // 0..51 (50,51 are zero pad)
    const int i0 = ic * 128;

    // stage 20 rows x 128 i as float2 (coalesced, 5 iters)
    for (int qq = 0; qq < 5; ++qq) {
        int idx = qq * 256 + t;                 // 0..1279 float2 slots
        int cc = idx >> 6, il = idx & 63;
        *(float2*)(mi + cc * 128 + il * 2) =
            *(const float2*)(Mt + (size_t)(ct * 20 + cc) * 1024 + i0 + il * 2);
    }

    float mj0 = Mt[(size_t)(c * 5 + 0) * 1024 + j];
    float mj1 = Mt[(size_t)(c * 5 + 1) * 1024 + j];
    float mj2 = Mt[(size_t)(c * 5 + 2) * 1024 + j];
    float mj3 = Mt[(size_t)(c * 5 + 3) * 1024 + j];
    float mj4 = Mt[(size_t)(c * 5 + 4) * 1024 + j];
    __syncthreads();

    const float4* m0 = (const float4*)(mi + (cl * 5 + 0) * 128);
    const float4* m1 = (const float4*)(mi + (cl * 5 + 1) * 128);
    const float4* m2 = (const float4*)(mi + (cl * 5 + 2) * 128);
    const float4* m3 = (const float4*)(mi + (cl * 5 + 3) * 128);
    const float4* m4 = (const float4*)(mi + (cl * 5 + 4) * 128);

    float acc0 = 0.f, acc1 = 0.f, acc2 = 0.f, acc3 = 0.f;
    for (int p = 0; p < 32; ++p) {
        float4 v0 = m0[p], v1 = m1[p], v2 = m2[p], v3 = m3[p], v4 = m4[p];
        float d0 = fabsf(v0.x - mj0) + fabsf(v1.x - mj1) + fabsf(v2.x - mj2)
                 + fabsf(v3.x - mj3) + fabsf(v4.x - mj4);
        float d1 = fabsf(v0.y - mj0) + fabsf(v1.y - mj1) + fabsf(v2.y - mj2)
                 + fabsf(v3.y - mj3) + fabsf(v4.y - mj4);
        float d2 = fabsf(v0.z - mj0) + fabsf(v1.z - mj1) + fabsf(v2.z - mj2)
                 + fabsf(v3.z - mj3) + fabsf(v4.z - mj4);
        float d3 = fabsf(v0.w - mj0) + fabsf(v1.w - mj1) + fabsf(v2.w - mj2)
                 + fabsf(v3.w - mj3) + fabsf(v4.w - mj4);
        acc0 += __expf(-d0);
        acc1 += __expf(-d1);
        acc2 += __expf(-d2);
        acc3 += __expf(-d3);
    }
    // weight by Ws[64+c] (pad channels c>=50 get weight 0), reduce the 4
    // channel-lanes per j through LDS, single atomic per (block, j).
    float w = (c < 50) ? Wsc[64 + c] : 0.f;
    sred[t] = ((acc0 + acc1) + (acc2 + acc3)) * w;
    __syncthreads();
    if (t < 64) {
        float s = (sred[t] + sred[64 + t]) + (sred[128 + t] + sred[192 + t]);
        atomicAdd(score + jt * 64 + t, s);
    }
}

// ---------------------------------------------------------------------------
// ws layout (float offsets):
//   h2    @ 0       (131072)
//   stats @ 131072  (256)
//   Mt    @ 131328  (260*1024 = 266240, col-major transpose of M)
// K4 / opart / h4 eliminated: K2 writes the score base to d_out, K3
// accumulates the minibatch-discrimination part with device atomics.
// ---------------------------------------------------------------------------
extern "C" void kernel_launch(void* const* d_in, const int* in_sizes, int n_in,
                              void* d_out, int out_size, void* d_ws, size_t ws_size,
                              hipStream_t stream)
{
    const float* x     = (const float*)d_in[0];
    const float* W1    = (const float*)d_in[1];
    const float* b1    = (const float*)d_in[2];
    const float* W2    = (const float*)d_in[3];
    const float* b2    = (const float*)d_in[4];
    const float* gamma = (const float*)d_in[5];
    const float* beta  = (const float*)d_in[6];
    const float* W3    = (const float*)d_in[7];
    const float* b3    = (const float*)d_in[8];
    const float* Wv    = (const float*)d_in[9];
    const float* bv    = (const float*)d_in[10];
    const float* Wo    = (const float*)d_in[11];
    const float* bo    = (const float*)d_in[12];
    const float* T2    = (const float*)d_in[13];
    const float* Ws    = (const float*)d_in[14];
    const float* bs    = (const float*)d_in[15];

    float* ws    = (float*)d_ws;
    float* h2    = ws + 0;
    float* stats = ws + 131072;
    float* Mt    = ws + 131328;
    float* out   = (float*)d_out;

    hipMemsetAsync(stats, 0, 256 * sizeof(float), stream);
    hipLaunchKernelGGL(k1_mlp12, dim3(512), dim3(256), 0, stream,
                       x, W1, b1, W2, b2, h2, stats);
    hipLaunchKernelGGL(k2_bn_attn_m, dim3(512), dim3(256), 0, stream,
                       h2, stats, gamma, beta, W3, b3, Wv, bv, Wo, bo, T2,
                       Ws, bs, Mt, out);
    hipLaunchKernelGGL(k3_pairs, dim3(1664), dim3(256), 0, stream, Mt, Ws, out);
}

// Round 6
// 136.063 us; speedup vs baseline: 1.0624x; 1.0354x over previous
//
#include <hip/hip_runtime.h>
#include <math.h>

#define LRELU(v) ((v) > 0.f ? (v) : 0.2f * (v))

// ---------------------------------------------------------------------------
// K1: h1 = lrelu(x@W1+b1) [1024,256]; h2 = h1@W2+b2 [1024,128]; BN stats.
// 256 blocks x 256 threads, 4 rows/block: halves W1/W2 L2 traffic vs 2-row
// (128 MB -> 64 MB; VALU total unchanged).
// ---------------------------------------------------------------------------
__global__ __launch_bounds__(256) void k1_mlp12(
    const float* __restrict__ x,
    const float* __restrict__ W1, const float* __restrict__ b1,
    const float* __restrict__ W2, const float* __restrict__ b2,
    float* __restrict__ h2g, float* __restrict__ stats)
{
    __shared__ float xs[512];                   // 4 rows x 128
    __shared__ float h1s[1024];                 // 4 rows x 256
    __shared__ float ssum[256];
    __shared__ float ssq[256];
    const int t = threadIdx.x;
    const int r0 = blockIdx.x * 4;

    xs[t]       = x[r0 * 128 + t];              // 4 rows of x, coalesced
    xs[256 + t] = x[r0 * 128 + 256 + t];
    __syncthreads();

    // h1: thread t = column, all 4 rows share each W1 load
    {
        float a0 = b1[t], a1 = a0, a2 = a0, a3 = a0;
        for (int k = 0; k < 128; ++k) {
            float w = W1[k * 256 + t];          // coalesced
            a0 += xs[k] * w;
            a1 += xs[128 + k] * w;
            a2 += xs[256 + k] * w;
            a3 += xs[384 + k] * w;
        }
        h1s[t]       = LRELU(a0);
        h1s[256 + t] = LRELU(a1);
        h1s[512 + t] = LRELU(a2);
        h1s[768 + t] = LRELU(a3);
    }
    __syncthreads();

    // h2: thread (c = t&127, rr = t>>7) -> rows rr and rr+2 share W2 loads
    {
        const int c = t & 127;
        const int rr = t >> 7;
        float a0 = b2[c], a1 = a0;
        const float* h1a = h1s + rr * 256;
        const float* h1b = h1s + (rr + 2) * 256;
        for (int k = 0; k < 256; ++k) {
            float w = W2[k * 128 + c];
            a0 += h1a[k] * w;
            a1 += h1b[k] * w;
        }
        h2g[(r0 + rr) * 128 + c]     = a0;
        h2g[(r0 + rr + 2) * 128 + c] = a1;
        ssum[t] = a0 + a1;                      // partial over this thread's 2 rows
        ssq[t]  = a0 * a0 + a1 * a1;
    }
    __syncthreads();
    if (t < 128)      atomicAdd(stats + t, ssum[t] + ssum[128 + t]);
    else { int c = t - 128; atomicAdd(stats + 128 + c, ssq[c] + ssq[128 + c]); }
}

// ---------------------------------------------------------------------------
// K2: BN+lrelu -> h3 -> attn(seq=1) -> h4 -> Mt = (h4@T2)^T (unscaled),
// PLUS score base = h4.Ws[0:64] + bs - sum_c Ws[64+c].
// 256 blocks x 256 threads, 4 rows/block (W3/Wv/Wo/T2 traffic halved).
// Mt[260][1024] col-major, rows 250..259 zeroed (K3 ct=12 pad).
// ---------------------------------------------------------------------------
__global__ __launch_bounds__(256) void k2_bn_attn_m(
    const float* __restrict__ h2g, const float* __restrict__ stats,
    const float* __restrict__ gamma, const float* __restrict__ beta,
    const float* __restrict__ W3, const float* __restrict__ b3,
    const float* __restrict__ Wv, const float* __restrict__ bv,
    const float* __restrict__ Wo, const float* __restrict__ bo,
    const float* __restrict__ T2,
    const float* __restrict__ Wsc, const float* __restrict__ bs,
    float* __restrict__ Mt, float* __restrict__ score)
{
    __shared__ float a[512];                    // [4 rows][128]
    __shared__ float h3s[256];                  // [4][64]
    __shared__ float vss[256];
    __shared__ float h4s[256];
    __shared__ float red[5];
    const int t = threadIdx.x;
    const int r0 = blockIdx.x * 4;

    // BN (batch stats) + lrelu: 512 elems, 2 per thread (same c for both)
    {
        const int c = t & 127;
        float s = stats[c], ss = stats[128 + c];
        float mean = s * (1.f / 1024.f);
        float var = ss * (1.f / 1024.f) - mean * mean;
        float rstd = rsqrtf(var + 1e-5f);
        float g = gamma[c], be = beta[c];
        float v0 = (h2g[r0 * 128 + t]       - mean) * rstd * g + be;
        float v1 = (h2g[r0 * 128 + 256 + t] - mean) * rstd * g + be;
        a[t]       = LRELU(v0);
        a[256 + t] = LRELU(v1);
    }
    __syncthreads();

    const int row = t >> 6, col = t & 63;       // row 0..3, all threads active
    // h3 = lrelu(a@W3+b3)
    {
        float acc = b3[col];
        for (int k = 0; k < 128; ++k) acc += a[row * 128 + k] * W3[k * 64 + col];
        h3s[row * 64 + col] = LRELU(acc);
    }
    __syncthreads();
    // v = h3@Wv+bv ; then h4 = h3 + v@Wo + bo
    {
        float acc = bv[col];
        for (int k = 0; k < 64; ++k) acc += h3s[row * 64 + k] * Wv[k * 64 + col];
        vss[row * 64 + col] = acc;
    }
    __syncthreads();
    {
        float acc = bo[col];
        for (int k = 0; k < 64; ++k) acc += vss[row * 64 + k] * Wo[k * 64 + col];
        h4s[row * 64 + col] = h3s[row * 64 + col] + acc;
    }
    __syncthreads();

    // Mt[col][r0..r0+3]: each T2 load feeds all 4 rows
    if (t < 250) {
        float m0 = 0.f, m1 = 0.f, m2 = 0.f, m3 = 0.f;
        for (int k = 0; k < 64; ++k) {
            float w = T2[k * 250 + t];          // coalesced across t
            m0 += h4s[k] * w;
            m1 += h4s[64 + k] * w;
            m2 += h4s[128 + k] * w;
            m3 += h4s[192 + k] * w;
        }
        size_t base = (size_t)t * 1024 + r0;
        Mt[base]     = m0;
        Mt[base + 1] = m1;
        Mt[base + 2] = m2;
        Mt[base + 3] = m3;
    } else {
        size_t base = (size_t)t * 1024 + r0;
        Mt[base] = 0.f; Mt[base + 1] = 0.f; Mt[base + 2] = 0.f; Mt[base + 3] = 0.f;
    }
    if (t < 4) {
        size_t base = (size_t)(256 + t) * 1024 + r0;
        Mt[base] = 0.f; Mt[base + 1] = 0.f; Mt[base + 2] = 0.f; Mt[base + 3] = 0.f;
    }

    // score base: wave w reduces row w's dot(h4, Ws[0:64])
    float contrib = h4s[t] * Wsc[col];
    for (int off = 32; off > 0; off >>= 1)
        contrib += __shfl_down(contrib, off, 64);
    if (col == 0) red[row] = contrib;
    __syncthreads();
    if (t < 64) {                               // sum_c Ws[64+c] in wave 0
        float w2 = (t < 50) ? Wsc[64 + t] : 0.f;
        for (int off = 32; off > 0; off >>= 1)
            w2 += __shfl_down(w2, off, 64);
        if (t == 0) red[4] = w2;
    }
    __syncthreads();
    // self-term exp(0)=1 per channel is included in K3's sums; subtract
    // sum_c Ws[64+c] (red[4]) here once.
    if (t < 4) score[r0 + t] = red[t] + bs[0] - red[4];
}

// ---------------------------------------------------------------------------
// K3: all-pairs L1 + __expf (fast v_exp path). UNCHANGED from round 5.
// Grid = 16 jt x 13 ct x 8 ic = 1664 blocks (~26 waves/CU).
// float4 LDS broadcast reads; per-block LDS reduction -> one atomicAdd
// per (block, j): 106K atomics total, hidden under compute.
// ---------------------------------------------------------------------------
__global__ __launch_bounds__(256) void k3_pairs(
    const float* __restrict__ Mt, const float* __restrict__ Wsc,
    float* __restrict__ score)
{
    __shared__ float mi[2560];                  // [20 cols][128 i]
    __shared__ float sred[256];
    const int t = threadIdx.x;
    const int b = blockIdx.x;
    const int jt = b / 104;
    const int rem = b - jt * 104;
    const int ct = rem >> 3;
    const int ic = rem & 7;
    const int jl = t & 63, cl = t >> 6;
    const int j = jt * 64 + jl;
    const int c = ct * 4 + cl;                  // 0..51 (50,51 are zero pad)
    const int i0 = ic * 128;

    // stage 20 rows x 128 i as float2 (coalesced, 5 iters)
    for (int qq = 0; qq < 5; ++qq) {
        int idx = qq * 256 + t;                 // 0..1279 float2 slots
        int cc = idx >> 6, il = idx & 63;
        *(float2*)(mi + cc * 128 + il * 2) =
            *(const float2*)(Mt + (size_t)(ct * 20 + cc) * 1024 + i0 + il * 2);
    }

    float mj0 = Mt[(size_t)(c * 5 + 0) * 1024 + j];
    float mj1 = Mt[(size_t)(c * 5 + 1) * 1024 + j];
    float mj2 = Mt[(size_t)(c * 5 + 2) * 1024 + j];
    float mj3 = Mt[(size_t)(c * 5 + 3) * 1024 + j];
    float mj4 = Mt[(size_t)(c * 5 + 4) * 1024 + j];
    __syncthreads();

    const float4* m0 = (const float4*)(mi + (cl * 5 + 0) * 128);
    const float4* m1 = (const float4*)(mi + (cl * 5 + 1) * 128);
    const float4* m2 = (const float4*)(mi + (cl * 5 + 2) * 128);
    const float4* m3 = (const float4*)(mi + (cl * 5 + 3) * 128);
    const float4* m4 = (const float4*)(mi + (cl * 5 + 4) * 128);

    float acc0 = 0.f, acc1 = 0.f, acc2 = 0.f, acc3 = 0.f;
    for (int p = 0; p < 32; ++p) {
        float4 v0 = m0[p], v1 = m1[p], v2 = m2[p], v3 = m3[p], v4 = m4[p];
        float d0 = fabsf(v0.x - mj0) + fabsf(v1.x - mj1) + fabsf(v2.x - mj2)
                 + fabsf(v3.x - mj3) + fabsf(v4.x - mj4);
        float d1 = fabsf(v0.y - mj0) + fabsf(v1.y - mj1) + fabsf(v2.y - mj2)
                 + fabsf(v3.y - mj3) + fabsf(v4.y - mj4);
        float d2 = fabsf(v0.z - mj0) + fabsf(v1.z - mj1) + fabsf(v2.z - mj2)
                 + fabsf(v3.z - mj3) + fabsf(v4.z - mj4);
        float d3 = fabsf(v0.w - mj0) + fabsf(v1.w - mj1) + fabsf(v2.w - mj2)
                 + fabsf(v3.w - mj3) + fabsf(v4.w - mj4);
        acc0 += __expf(-d0);
        acc1 += __expf(-d1);
        acc2 += __expf(-d2);
        acc3 += __expf(-d3);
    }
    // weight by Ws[64+c] (pad channels c>=50 get weight 0), reduce the 4
    // channel-lanes per j through LDS, single atomic per (block, j).
    float w = (c < 50) ? Wsc[64 + c] : 0.f;
    sred[t] = ((acc0 + acc1) + (acc2 + acc3)) * w;
    __syncthreads();
    if (t < 64) {
        float s = (sred[t] + sred[64 + t]) + (sred[128 + t] + sred[192 + t]);
        atomicAdd(score + jt * 64 + t, s);
    }
}

// ---------------------------------------------------------------------------
// ws layout (float offsets):
//   h2    @ 0       (131072)
//   stats @ 131072  (256)
//   Mt    @ 131328  (260*1024 = 266240, col-major transpose of M)
// K4 / opart / h4 eliminated: K2 writes the score base to d_out, K3
// accumulates the minibatch-discrimination part with device atomics.
// ---------------------------------------------------------------------------
extern "C" void kernel_launch(void* const* d_in, const int* in_sizes, int n_in,
                              void* d_out, int out_size, void* d_ws, size_t ws_size,
                              hipStream_t stream)
{
    const float* x     = (const float*)d_in[0];
    const float* W1    = (const float*)d_in[1];
    const float* b1    = (const float*)d_in[2];
    const float* W2    = (const float*)d_in[3];
    const float* b2    = (const float*)d_in[4];
    const float* gamma = (const float*)d_in[5];
    const float* beta  = (const float*)d_in[6];
    const float* W3    = (const float*)d_in[7];
    const float* b3    = (const float*)d_in[8];
    const float* Wv    = (const float*)d_in[9];
    const float* bv    = (const float*)d_in[10];
    const float* Wo    = (const float*)d_in[11];
    const float* bo    = (const float*)d_in[12];
    const float* T2    = (const float*)d_in[13];
    const float* Ws    = (const float*)d_in[14];
    const float* bs    = (const float*)d_in[15];

    float* ws    = (float*)d_ws;
    float* h2    = ws + 0;
    float* stats = ws + 131072;
    float* Mt    = ws + 131328;
    float* out   = (float*)d_out;

    hipMemsetAsync(stats, 0, 256 * sizeof(float), stream);
    hipLaunchKernelGGL(k1_mlp12, dim3(256), dim3(256), 0, stream,
                       x, W1, b1, W2, b2, h2, stats);
    hipLaunchKernelGGL(k2_bn_attn_m, dim3(256), dim3(256), 0, stream,
                       h2, stats, gamma, beta, W3, b3, Wv, bv, Wo, bo, T2,
                       Ws, bs, Mt, out);
    hipLaunchKernelGGL(k3_pairs, dim3(1664), dim3(256), 0, stream, Mt, Ws, out);
}